// Round 3
// baseline (579.319 us; speedup 1.0000x reference)
//
#include <hip/hip_runtime.h>
#include <cstdint>
#include <cstddef>

typedef __bf16 bf16x8 __attribute__((ext_vector_type(8)));
typedef __bf16 bf16x4 __attribute__((ext_vector_type(4)));
typedef float f32x4 __attribute__((ext_vector_type(4)));
typedef unsigned short u16x4 __attribute__((ext_vector_type(4)));
typedef short s16x4 __attribute__((ext_vector_type(4)));

// fp32 -> bf16 round-to-nearest-even
__device__ __forceinline__ unsigned short f2bf(float f) {
  union { float f; unsigned u; } v; v.f = f;
  unsigned r = (v.u + 0x7FFF + ((v.u >> 16) & 1)) >> 16;
  return (unsigned short)r;
}

// async global->LDS, 16B per lane
__device__ __forceinline__ void gl2lds16(const void* g, void* l) {
  __builtin_amdgcn_global_load_lds(
      (const __attribute__((address_space(1))) void*)g,
      (__attribute__((address_space(3))) void*)l,
      16, 0, 0);
}

// ---------------------------------------------------------------- prep
__global__ __launch_bounds__(256) void cast_f32_bf16(
    const float* __restrict__ in, unsigned short* __restrict__ out, int n) {
  int i = (blockIdx.x * 256 + threadIdx.x) * 4;
  if (i >= n) return;
  float4 v = *(const float4*)(in + i);
  u16x4 o;
  o[0] = f2bf(v.x); o[1] = f2bf(v.y); o[2] = f2bf(v.z); o[3] = f2bf(v.w);
  *(u16x4*)(out + i) = o;
}

__global__ __launch_bounds__(256) void transpose_cast(
    const float* __restrict__ in, unsigned short* __restrict__ out, int R, int C) {
  __shared__ float t[32][33];
  int c0 = blockIdx.x * 32, r0 = blockIdx.y * 32;
  int tx = threadIdx.x, ty = threadIdx.y;
#pragma unroll
  for (int j = 0; j < 4; ++j)
    t[ty + j * 8][tx] = in[(size_t)(r0 + ty + j * 8) * C + c0 + tx];
  __syncthreads();
#pragma unroll
  for (int j = 0; j < 4; ++j)
    out[(size_t)(c0 + ty + j * 8) * R + r0 + tx] = f2bf(t[tx][ty + j * 8]);
}

// key_padding_mask (int 0/1) -> additive float (-1e30 where masked)
__global__ __launch_bounds__(256) void prep_pad(
    const int* __restrict__ mask, float* __restrict__ padd, int n) {
  int i = blockIdx.x * 256 + threadIdx.x;
  if (i < n) padd[i] = mask[i] ? -1e30f : 0.0f;
}

// ---------------------------------------------------------------- GEMM (C = A[M,K] * B[N,K]^T)
template <int EPI>
__global__ __launch_bounds__(256) void gemm_bt(
    const unsigned short* __restrict__ A, const unsigned short* __restrict__ Bm,
    const float* __restrict__ bias, float* __restrict__ outF,
    unsigned short* __restrict__ Qb, unsigned short* __restrict__ Kb,
    unsigned short* __restrict__ Vt, int M, int N, int K) {
  __shared__ unsigned short As[128 * 32];
  __shared__ unsigned short Bs[128 * 32];
  const int tid = threadIdx.x;
  const int bm = blockIdx.x * 128;
  const int bn = blockIdx.y * 128;
  const int wave = tid >> 6, lane = tid & 63;
  const int wm = (wave >> 1) * 64, wn = (wave & 1) * 64;
  const int lr = lane & 15, lq = lane >> 4;

  f32x4 acc[4][4] = {};

  const int c0 = tid, c1 = tid + 256;
  const int rA0 = c0 >> 2, colA0 = (c0 & 3) * 8;
  const int rA1 = c1 >> 2, colA1 = (c1 & 3) * 8;

  for (int k0 = 0; k0 < K; k0 += 32) {
    __syncthreads();
    gl2lds16(A + (size_t)(bm + rA0) * K + k0 + colA0, As + c0 * 8);
    gl2lds16(A + (size_t)(bm + rA1) * K + k0 + colA1, As + c1 * 8);
    gl2lds16(Bm + (size_t)(bn + rA0) * K + k0 + colA0, Bs + c0 * 8);
    gl2lds16(Bm + (size_t)(bn + rA1) * K + k0 + colA1, Bs + c1 * 8);
    __syncthreads();
    bf16x8 af[4], bfr[4];
#pragma unroll
    for (int mi = 0; mi < 4; ++mi)
      af[mi] = *(const bf16x8*)(As + (wm + mi * 16 + lr) * 32 + lq * 8);
#pragma unroll
    for (int nj = 0; nj < 4; ++nj)
      bfr[nj] = *(const bf16x8*)(Bs + (wn + nj * 16 + lr) * 32 + lq * 8);
#pragma unroll
    for (int mi = 0; mi < 4; ++mi)
#pragma unroll
      for (int nj = 0; nj < 4; ++nj)
        acc[mi][nj] = __builtin_amdgcn_mfma_f32_16x16x32_bf16(af[mi], bfr[nj], acc[mi][nj], 0, 0, 0);
  }

#pragma unroll
  for (int mi = 0; mi < 4; ++mi) {
#pragma unroll
    for (int nj = 0; nj < 4; ++nj) {
#pragma unroll
      for (int r = 0; r < 4; ++r) {
        int m = bm + wm + mi * 16 + lq * 4 + r;
        int n = bn + wn + nj * 16 + lr;
        float v = acc[mi][nj][r] + bias[n];
        if (EPI == 0) {
          int b = m >> 11, t = m & 2047;
          int part = n >> 10, d = n & 1023;
          int h = d >> 6, hd = d & 63;
          size_t qk = ((size_t)(b * 16 + h) * 2048 + t) * 64 + hd;
          // fold softmax scale 1/sqrt(64) and log2(e) into Q
          if (part == 0)      Qb[qk] = f2bf(v * 0.18033688011112042f);
          else if (part == 1) Kb[qk] = f2bf(v);
          else                Vt[((size_t)(b * 16 + h) * 64 + hd) * 2048 + t] = f2bf(v);
        } else {
          outF[(size_t)m * N + n] = v;
        }
      }
    }
  }
}

// ---------------------------------------------------------------- flash attention
// S^T = K Q^T: C-layout (key=4*lq+r, query=lr) is directly the A-operand of
// mfma_16x16x16bf16_1k (k=4*lq+j) for PV — no LDS, no barriers.
// Each wave owns 16 q-rows; waves are length-balanced by pairing tile t with 15-t.

__device__ __forceinline__ void load_k(
    const unsigned short* __restrict__ Kh, int kc, int lr, int lq, bf16x8 (&kf)[4][2]) {
#pragma unroll
  for (int t = 0; t < 4; ++t) {
    const unsigned short* kp = Kh + (size_t)(kc + t * 16 + lr) * 64 + lq * 8;
    kf[t][0] = *(const bf16x8*)(kp);
    kf[t][1] = *(const bf16x8*)(kp + 32);
  }
}

__device__ __forceinline__ void qk_mfma(
    const bf16x8 (&kf)[4][2], const bf16x8 (&qf)[2], f32x4 (&S)[4]) {
#pragma unroll
  for (int t = 0; t < 4; ++t) {
    S[t] = __builtin_amdgcn_mfma_f32_16x16x32_bf16(kf[t][0], qf[0], S[t], 0, 0, 0);
    S[t] = __builtin_amdgcn_mfma_f32_16x16x32_bf16(kf[t][1], qf[1], S[t], 0, 0, 0);
  }
}

template <bool DIAG>
__device__ __forceinline__ void softmax_pv(
    const unsigned short* __restrict__ Vh, const float* __restrict__ pb,
    int kc, int q0, int lr, int lq, int bsrc,
    f32x4 (&S)[4], f32x4 (&O)[4], float& m, float& l) {
  float4 pd[4];
#pragma unroll
  for (int t = 0; t < 4; ++t) pd[t] = *(const float4*)(pb + kc + t * 16 + 4 * lq);

#pragma unroll
  for (int t = 0; t < 4; ++t) {
    const float* pdp = (const float*)&pd[t];
#pragma unroll
    for (int r = 0; r < 4; ++r) {
      float s = S[t][r] + pdp[r];
      if (DIAG) {
        int key = kc + t * 16 + 4 * lq + r;
        if (key > q0 + lr) s = -1e30f;
      }
      S[t][r] = s;
    }
  }
  float mx = -1e30f;
#pragma unroll
  for (int t = 0; t < 4; ++t)
#pragma unroll
    for (int r = 0; r < 4; ++r) mx = fmaxf(mx, S[t][r]);
  mx = fmaxf(mx, __shfl_xor(mx, 16, 64));
  mx = fmaxf(mx, __shfl_xor(mx, 32, 64));
  float mnew = fmaxf(m, mx);
  float al = __builtin_amdgcn_exp2f(m - mnew);
  m = mnew;
  float rs = 0.f;
#pragma unroll
  for (int t = 0; t < 4; ++t)
#pragma unroll
    for (int r = 0; r < 4; ++r) {
      float pv = __builtin_amdgcn_exp2f(S[t][r] - mnew);
      S[t][r] = pv;
      rs += pv;
    }
  rs += __shfl_xor(rs, 16, 64);
  rs += __shfl_xor(rs, 32, 64);
  l = l * al + rs;
  // broadcast alpha from query=lr layout to query=4*lq+r layout, rescale O
#pragma unroll
  for (int r = 0; r < 4; ++r) {
    float a = __shfl(al, bsrc + r, 64);
#pragma unroll
    for (int nj = 0; nj < 4; ++nj) O[nj][r] *= a;
  }
  // P cvt + PV
  s16x4 pf[4];
#pragma unroll
  for (int t = 0; t < 4; ++t) {
    bf16x4 p4;
#pragma unroll
    for (int r = 0; r < 4; ++r) p4[r] = (__bf16)S[t][r];
    pf[t] = __builtin_bit_cast(s16x4, p4);
  }
#pragma unroll
  for (int t = 0; t < 4; ++t) {
#pragma unroll
    for (int nj = 0; nj < 4; ++nj) {
      s16x4 vf = *(const s16x4*)(Vh + (size_t)(nj * 16 + lr) * 2048 + kc + t * 16 + 4 * lq);
      O[nj] = __builtin_amdgcn_mfma_f32_16x16x16bf16_1k(pf[t], vf, O[nj], 0, 0, 0);
    }
  }
}

// one wave, 16 query rows starting at q0
__device__ __forceinline__ void process_rows(
    const unsigned short* __restrict__ Qh, const unsigned short* __restrict__ Kh,
    const unsigned short* __restrict__ Vh, const float* __restrict__ pb,
    unsigned short* __restrict__ ctxBase, int q0, int lr, int lq, int bsrc) {
  bf16x8 qf[2];
  {
    const unsigned short* qp = Qh + (size_t)(q0 + lr) * 64 + lq * 8;
    qf[0] = *(const bf16x8*)(qp);
    qf[1] = *(const bf16x8*)(qp + 32);
  }
  f32x4 O[4] = {};
  float m = -1e30f, l = 0.f;
  const int F = q0 & ~63;

  bf16x8 kf[4][2];
  load_k(Kh, 0, lr, lq, kf);                 // preload chunk 0
  for (int kc = 0; kc < F; kc += 64) {
    f32x4 S[4] = {};
    qk_mfma(kf, qf, S);
    load_k(Kh, kc + 64, lr, lq, kf);         // prefetch next; hides behind softmax
    softmax_pv<false>(Vh, pb, kc, q0, lr, lq, bsrc, S, O, m, l);
  }
  {
    f32x4 S[4] = {};
    qk_mfma(kf, qf, S);
    softmax_pv<true>(Vh, pb, F, q0, lr, lq, bsrc, S, O, m, l);
  }
  float linv = 1.0f / l;
#pragma unroll
  for (int r = 0; r < 4; ++r) {
    float li = __shfl(linv, bsrc + r, 64);
    int q = q0 + 4 * lq + r;
    unsigned short* cp = ctxBase + (size_t)q * 1024 + lr;
#pragma unroll
    for (int nj = 0; nj < 4; ++nj) cp[nj * 16] = f2bf(O[nj][r] * li);
  }
}

__global__ __launch_bounds__(256) void flash_attn(
    const unsigned short* __restrict__ Qb, const unsigned short* __restrict__ Kb,
    const unsigned short* __restrict__ Vt, const float* __restrict__ padd,
    unsigned short* __restrict__ ctx) {
  const int bid = blockIdx.x;
  const int p = bid >> 7;        // tile pair (8+p, 7-p): uniform per-wave work
  const int rem = bid & 127;
  const int bh = rem >> 1;
  const int half = rem & 1;
  const int b = bh >> 4, h = bh & 15;
  const int wave = threadIdx.x >> 6, lane = threadIdx.x & 63;
  const int lr = lane & 15, lq = lane >> 4;
  const int bsrc = 20 * lq;      // shfl src: lane with lr == 4*lq+r
  const int sub = half * 64 + wave * 16;

  const unsigned short* Qh = Qb + (size_t)bh * 2048 * 64;
  const unsigned short* Kh = Kb + (size_t)bh * 2048 * 64;
  const unsigned short* Vh = Vt + (size_t)bh * 64 * 2048;
  const float* pb = padd + b * 2048;
  unsigned short* ctxBase = ctx + ((size_t)b * 2048) * 1024 + h * 64;

  process_rows(Qh, Kh, Vh, pb, ctxBase, (8 + p) * 128 + sub, lr, lq, bsrc);
  process_rows(Qh, Kh, Vh, pb, ctxBase, (7 - p) * 128 + sub, lr, lq, bsrc);
}

// ---------------------------------------------------------------- launch
extern "C" void kernel_launch(void* const* d_in, const int* in_sizes, int n_in,
                              void* d_out, int out_size, void* d_ws, size_t ws_size,
                              hipStream_t stream) {
  const float* x    = (const float*)d_in[0];
  const float* Wqkv = (const float*)d_in[1];
  const float* bqkv = (const float*)d_in[2];
  const float* Wo   = (const float*)d_in[3];
  const float* bo   = (const float*)d_in[4];
  const int*   mask = (const int*)d_in[5];
  float* out = (float*)d_out;

  unsigned short* ws = (unsigned short*)d_ws;
  const size_t SZ_X = (size_t)8192 * 1024;  // B*T*D
  unsigned short* xb    = ws;                                   // 16 MB, reused as ctx
  unsigned short* WqkvT = xb + SZ_X;                            // 6 MB
  unsigned short* WoT   = WqkvT + (size_t)3072 * 1024;          // 2 MB
  unsigned short* Qb    = WoT + (size_t)1024 * 1024;            // 16 MB
  unsigned short* Kb    = Qb + SZ_X;                            // 16 MB
  unsigned short* Vt    = Kb + SZ_X;                            // 16 MB
  float*          padd  = (float*)(Vt + SZ_X);                  // 32 KB
  unsigned short* ctx   = xb;  // xb dead after GEMM1

  cast_f32_bf16<<<8192, 256, 0, stream>>>(x, xb, (int)SZ_X);
  transpose_cast<<<dim3(96, 32), dim3(32, 8), 0, stream>>>(Wqkv, WqkvT, 1024, 3072);
  transpose_cast<<<dim3(32, 32), dim3(32, 8), 0, stream>>>(Wo, WoT, 1024, 1024);
  prep_pad<<<32, 256, 0, stream>>>(mask, padd, 8192);
  gemm_bt<0><<<dim3(64, 24), 256, 0, stream>>>(xb, WqkvT, bqkv, nullptr, Qb, Kb, Vt,
                                               8192, 3072, 1024);
  flash_attn<<<1024, 256, 0, stream>>>(Qb, Kb, Vt, padd, ctx);
  gemm_bt<1><<<dim3(64, 8), 256, 0, stream>>>(ctx, WoT, bo, out, nullptr, nullptr, nullptr,
                                              8192, 1024, 1024);
}

// Round 4
// 412.210 us; speedup vs baseline: 1.4054x; 1.4054x over previous
//
#include <hip/hip_runtime.h>
#include <cstdint>
#include <cstddef>

typedef __bf16 bf16x8 __attribute__((ext_vector_type(8)));
typedef __bf16 bf16x4 __attribute__((ext_vector_type(4)));
typedef float f32x4 __attribute__((ext_vector_type(4)));
typedef unsigned short u16x4 __attribute__((ext_vector_type(4)));
typedef short s16x4 __attribute__((ext_vector_type(4)));

// fp32 -> bf16 round-to-nearest-even
__device__ __forceinline__ unsigned short f2bf(float f) {
  union { float f; unsigned u; } v; v.f = f;
  unsigned r = (v.u + 0x7FFF + ((v.u >> 16) & 1)) >> 16;
  return (unsigned short)r;
}

// async global->LDS, 16B per lane
__device__ __forceinline__ void gl2lds16(const void* g, void* l) {
  __builtin_amdgcn_global_load_lds(
      (const __attribute__((address_space(1))) void*)g,
      (__attribute__((address_space(3))) void*)l,
      16, 0, 0);
}

// ---------------------------------------------------------------- prep
__global__ __launch_bounds__(256) void cast_f32_bf16(
    const float* __restrict__ in, unsigned short* __restrict__ out, int n) {
  int i = (blockIdx.x * 256 + threadIdx.x) * 4;
  if (i >= n) return;
  float4 v = *(const float4*)(in + i);
  u16x4 o;
  o[0] = f2bf(v.x); o[1] = f2bf(v.y); o[2] = f2bf(v.z); o[3] = f2bf(v.w);
  *(u16x4*)(out + i) = o;
}

__global__ __launch_bounds__(256) void transpose_cast(
    const float* __restrict__ in, unsigned short* __restrict__ out, int R, int C) {
  __shared__ float t[32][33];
  int c0 = blockIdx.x * 32, r0 = blockIdx.y * 32;
  int tx = threadIdx.x, ty = threadIdx.y;
#pragma unroll
  for (int j = 0; j < 4; ++j)
    t[ty + j * 8][tx] = in[(size_t)(r0 + ty + j * 8) * C + c0 + tx];
  __syncthreads();
#pragma unroll
  for (int j = 0; j < 4; ++j)
    out[(size_t)(c0 + ty + j * 8) * R + r0 + tx] = f2bf(t[tx][ty + j * 8]);
}

// key_padding_mask (int 0/1) -> additive float (-1e30 where masked)
__global__ __launch_bounds__(256) void prep_pad(
    const int* __restrict__ mask, float* __restrict__ padd, int n) {
  int i = blockIdx.x * 256 + threadIdx.x;
  if (i < n) padd[i] = mask[i] ? -1e30f : 0.0f;
}

// ---------------------------------------------------------------- GEMM (C = A[M,K] * B[N,K]^T)
template <int EPI>
__global__ __launch_bounds__(256) void gemm_bt(
    const unsigned short* __restrict__ A, const unsigned short* __restrict__ Bm,
    const float* __restrict__ bias, float* __restrict__ outF,
    unsigned short* __restrict__ Qb, unsigned short* __restrict__ Kb,
    unsigned short* __restrict__ Vt, int M, int N, int K) {
  __shared__ unsigned short As[128 * 32];
  __shared__ unsigned short Bs[128 * 32];
  const int tid = threadIdx.x;
  const int bm = blockIdx.x * 128;
  const int bn = blockIdx.y * 128;
  const int wave = tid >> 6, lane = tid & 63;
  const int wm = (wave >> 1) * 64, wn = (wave & 1) * 64;
  const int lr = lane & 15, lq = lane >> 4;

  f32x4 acc[4][4] = {};

  const int c0 = tid, c1 = tid + 256;
  const int rA0 = c0 >> 2, colA0 = (c0 & 3) * 8;
  const int rA1 = c1 >> 2, colA1 = (c1 & 3) * 8;

  for (int k0 = 0; k0 < K; k0 += 32) {
    __syncthreads();
    gl2lds16(A + (size_t)(bm + rA0) * K + k0 + colA0, As + c0 * 8);
    gl2lds16(A + (size_t)(bm + rA1) * K + k0 + colA1, As + c1 * 8);
    gl2lds16(Bm + (size_t)(bn + rA0) * K + k0 + colA0, Bs + c0 * 8);
    gl2lds16(Bm + (size_t)(bn + rA1) * K + k0 + colA1, Bs + c1 * 8);
    __syncthreads();
    bf16x8 af[4], bfr[4];
#pragma unroll
    for (int mi = 0; mi < 4; ++mi)
      af[mi] = *(const bf16x8*)(As + (wm + mi * 16 + lr) * 32 + lq * 8);
#pragma unroll
    for (int nj = 0; nj < 4; ++nj)
      bfr[nj] = *(const bf16x8*)(Bs + (wn + nj * 16 + lr) * 32 + lq * 8);
#pragma unroll
    for (int mi = 0; mi < 4; ++mi)
#pragma unroll
      for (int nj = 0; nj < 4; ++nj)
        acc[mi][nj] = __builtin_amdgcn_mfma_f32_16x16x32_bf16(af[mi], bfr[nj], acc[mi][nj], 0, 0, 0);
  }

#pragma unroll
  for (int mi = 0; mi < 4; ++mi) {
#pragma unroll
    for (int nj = 0; nj < 4; ++nj) {
#pragma unroll
      for (int r = 0; r < 4; ++r) {
        int m = bm + wm + mi * 16 + lq * 4 + r;
        int n = bn + wn + nj * 16 + lr;
        float v = acc[mi][nj][r] + bias[n];
        if (EPI == 0) {
          int b = m >> 11, t = m & 2047;
          int part = n >> 10, d = n & 1023;
          int h = d >> 6, hd = d & 63;
          size_t qk = ((size_t)(b * 16 + h) * 2048 + t) * 64 + hd;
          // fold softmax scale 1/sqrt(64) and log2(e) into Q
          if (part == 0)      Qb[qk] = f2bf(v * 0.18033688011112042f);
          else if (part == 1) Kb[qk] = f2bf(v);
          else                Vt[((size_t)(b * 16 + h) * 64 + hd) * 2048 + t] = f2bf(v);
        } else {
          outF[(size_t)m * N + n] = v;
        }
      }
    }
  }
}

// ---------------------------------------------------------------- flash attention
// S^T = K Q^T so the S C-layout regs (key=4*lq+r, query=lr) directly form the
// A-operand of mfma_16x16x16bf16_1k (k=4*lq+j) for PV — no LDS, no barriers.
// One wave per block (64 threads), 32 q-rows per wave; grid oversubscribed and
// LPT-ordered (largest q0 first) so retiring short waves are backfilled.
template <bool DIAG>
__device__ __forceinline__ void attn_chunk(
    const unsigned short* __restrict__ Kh, const unsigned short* __restrict__ Vh,
    const float* __restrict__ pb, int kc, int q0, int lr, int lq, int bsrc,
    const bf16x8 (&qf)[2][2], f32x4 (&O)[2][4], float (&m)[2], float (&l)[2]) {
  f32x4 S[4][2] = {};
#pragma unroll
  for (int t = 0; t < 4; ++t) {
    const unsigned short* kp = Kh + (size_t)(kc + t * 16 + lr) * 64 + lq * 8;
    bf16x8 kf0 = *(const bf16x8*)(kp);
    bf16x8 kf1 = *(const bf16x8*)(kp + 32);
#pragma unroll
    for (int qt = 0; qt < 2; ++qt) {
      S[t][qt] = __builtin_amdgcn_mfma_f32_16x16x32_bf16(kf0, qf[qt][0], S[t][qt], 0, 0, 0);
      S[t][qt] = __builtin_amdgcn_mfma_f32_16x16x32_bf16(kf1, qf[qt][1], S[t][qt], 0, 0, 0);
    }
  }
  float4 pd[4];
#pragma unroll
  for (int t = 0; t < 4; ++t) pd[t] = *(const float4*)(pb + kc + t * 16 + 4 * lq);

  float alpha_s[2];
#pragma unroll
  for (int qt = 0; qt < 2; ++qt) {
    const int q = q0 + qt * 16 + lr;
#pragma unroll
    for (int t = 0; t < 4; ++t) {
      const float* pdp = (const float*)&pd[t];
#pragma unroll
      for (int r = 0; r < 4; ++r) {
        float s = S[t][qt][r] + pdp[r];
        if (DIAG) {
          int key = kc + t * 16 + 4 * lq + r;
          if (key > q) s = -1e30f;
        }
        S[t][qt][r] = s;
      }
    }
    float mx = -1e30f;
#pragma unroll
    for (int t = 0; t < 4; ++t)
#pragma unroll
      for (int r = 0; r < 4; ++r) mx = fmaxf(mx, S[t][qt][r]);
    mx = fmaxf(mx, __shfl_xor(mx, 16, 64));
    mx = fmaxf(mx, __shfl_xor(mx, 32, 64));
    float mnew = fmaxf(m[qt], mx);
    float al = __builtin_amdgcn_exp2f(m[qt] - mnew);
    m[qt] = mnew;
    float rs = 0.f;
#pragma unroll
    for (int t = 0; t < 4; ++t)
#pragma unroll
      for (int r = 0; r < 4; ++r) {
        float pv = __builtin_amdgcn_exp2f(S[t][qt][r] - mnew);
        S[t][qt][r] = pv;
        rs += pv;
      }
    rs += __shfl_xor(rs, 16, 64);
    rs += __shfl_xor(rs, 32, 64);
    l[qt] = l[qt] * al + rs;
    alpha_s[qt] = al;
  }
  // broadcast alpha from query=lr layout to query=4*lq+r layout, rescale O
#pragma unroll
  for (int qt = 0; qt < 2; ++qt) {
#pragma unroll
    for (int r = 0; r < 4; ++r) {
      float a = __shfl(alpha_s[qt], bsrc + r, 64);
#pragma unroll
      for (int nj = 0; nj < 4; ++nj) O[qt][nj][r] *= a;
    }
  }
  // PV: P regs are already A-frags of 16x16x16 (k = 4*lq + j)
#pragma unroll
  for (int t = 0; t < 4; ++t) {
    s16x4 pf[2];
#pragma unroll
    for (int qt = 0; qt < 2; ++qt) {
      bf16x4 pb4;
#pragma unroll
      for (int r = 0; r < 4; ++r) pb4[r] = (__bf16)S[t][qt][r];
      pf[qt] = __builtin_bit_cast(s16x4, pb4);
    }
#pragma unroll
    for (int nj = 0; nj < 4; ++nj) {
      s16x4 vf = *(const s16x4*)(Vh + (size_t)(nj * 16 + lr) * 2048 + kc + t * 16 + 4 * lq);
#pragma unroll
      for (int qt = 0; qt < 2; ++qt)
        O[qt][nj] = __builtin_amdgcn_mfma_f32_16x16x16bf16_1k(pf[qt], vf, O[qt][nj], 0, 0, 0);
    }
  }
}

__global__ __launch_bounds__(64) void flash_attn(
    const unsigned short* __restrict__ Qb, const unsigned short* __restrict__ Kb,
    const unsigned short* __restrict__ Vt, const float* __restrict__ padd,
    unsigned short* __restrict__ ctx) {
  const int bid = blockIdx.x;
  const int qi = 63 - (bid >> 6);  // descending q0: longest waves dispatch first
  const int bh = bid & 63;
  const int b = bh >> 4, h = bh & 15;
  const int lane = threadIdx.x;
  const int lr = lane & 15, lq = lane >> 4;
  const int bsrc = 20 * lq;  // shfl src base: lane with lr == 4*lq+r
  const int q0 = qi * 32;

  const unsigned short* Qh = Qb + (size_t)bh * 2048 * 64;
  const unsigned short* Kh = Kb + (size_t)bh * 2048 * 64;
  const unsigned short* Vh = Vt + (size_t)bh * 64 * 2048;
  const float* pb = padd + b * 2048;

  // Q B-frags persistent in registers (scale pre-folded)
  bf16x8 qf[2][2];
#pragma unroll
  for (int qt = 0; qt < 2; ++qt)
#pragma unroll
    for (int kk = 0; kk < 2; ++kk)
      qf[qt][kk] = *(const bf16x8*)(Qh + (size_t)(q0 + qt * 16 + lr) * 64 + kk * 32 + lq * 8);

  f32x4 O[2][4] = {};
  float m[2] = {-1e30f, -1e30f}, l[2] = {0.f, 0.f};

  const int F = q0 & ~63;  // keys [0,F) need no causal check for this wave
  for (int kc = 0; kc < F; kc += 64)
    attn_chunk<false>(Kh, Vh, pb, kc, q0, lr, lq, bsrc, qf, O, m, l);
  attn_chunk<true>(Kh, Vh, pb, F, q0, lr, lq, bsrc, qf, O, m, l);

#pragma unroll
  for (int qt = 0; qt < 2; ++qt) {
    float linv = 1.0f / l[qt];
#pragma unroll
    for (int r = 0; r < 4; ++r) {
      float li = __shfl(linv, bsrc + r, 64);
      int q = q0 + qt * 16 + 4 * lq + r;
      unsigned short* cp = ctx + ((size_t)b * 2048 + q) * 1024 + h * 64 + lr;
#pragma unroll
      for (int nj = 0; nj < 4; ++nj)
        cp[nj * 16] = f2bf(O[qt][nj][r] * li);
    }
  }
}

// ---------------------------------------------------------------- launch
extern "C" void kernel_launch(void* const* d_in, const int* in_sizes, int n_in,
                              void* d_out, int out_size, void* d_ws, size_t ws_size,
                              hipStream_t stream) {
  const float* x    = (const float*)d_in[0];
  const float* Wqkv = (const float*)d_in[1];
  const float* bqkv = (const float*)d_in[2];
  const float* Wo   = (const float*)d_in[3];
  const float* bo   = (const float*)d_in[4];
  const int*   mask = (const int*)d_in[5];
  float* out = (float*)d_out;

  unsigned short* ws = (unsigned short*)d_ws;
  const size_t SZ_X = (size_t)8192 * 1024;  // B*T*D
  unsigned short* xb    = ws;                                   // 16 MB, reused as ctx
  unsigned short* WqkvT = xb + SZ_X;                            // 6 MB
  unsigned short* WoT   = WqkvT + (size_t)3072 * 1024;          // 2 MB
  unsigned short* Qb    = WoT + (size_t)1024 * 1024;            // 16 MB
  unsigned short* Kb    = Qb + SZ_X;                            // 16 MB
  unsigned short* Vt    = Kb + SZ_X;                            // 16 MB
  float*          padd  = (float*)(Vt + SZ_X);                  // 32 KB
  unsigned short* ctx   = xb;  // xb dead after GEMM1

  cast_f32_bf16<<<8192, 256, 0, stream>>>(x, xb, (int)SZ_X);
  transpose_cast<<<dim3(96, 32), dim3(32, 8), 0, stream>>>(Wqkv, WqkvT, 1024, 3072);
  transpose_cast<<<dim3(32, 32), dim3(32, 8), 0, stream>>>(Wo, WoT, 1024, 1024);
  prep_pad<<<32, 256, 0, stream>>>(mask, padd, 8192);
  gemm_bt<0><<<dim3(64, 24), 256, 0, stream>>>(xb, WqkvT, bqkv, nullptr, Qb, Kb, Vt,
                                               8192, 3072, 1024);
  flash_attn<<<4096, 64, 0, stream>>>(Qb, Kb, Vt, padd, ctx);
  gemm_bt<1><<<dim3(64, 8), 256, 0, stream>>>(ctx, WoT, bo, out, nullptr, nullptr, nullptr,
                                              8192, 1024, 1024);
}